// Round 10
// baseline (109.877 us; speedup 1.0000x reference)
//
#include <hip/hip_runtime.h>
#include <hip/hip_bf16.h>

// DCN v2 (modulated deformable 3x3 conv) + BN(eval) + ReLU, fused, MFMA.
// B=4, C=64, O=64, H=W=128. fp32 in/out; bf16 MFMA 16x16x32, fp32 accum.
//
// R23: serialization cuts on R22 (R22's barrier diet overshot prediction ->
// sync overhead still material).
//  (a) offset conv 4-way: wave wv = (ocO=wv&1, mtO=wv>>1) -> all 4 waves
//      active (R17's dedup halved wave parallelism to save bytes that no
//      longer matter), per-wave 18 ds_read+18 MFMA (was 36+36), accO 8->4
//      VGPR. WbO bytes +1.2 MB total (noise).
//  (b) epilogue direct stores: D-layout gives 4 consecutive px per acc ->
//      float4 store, 4-lane (cg) clusters cover 64B lines. dT transpose,
//      2 barriers, 16KB/block LDS traffic deleted.
//  (c) final main-loop barrier dropped (nothing touches LDS after).
// Base kept: 4-wave/32-px, launch_bounds(256,8), single-batch 3-row stage,
// cvt_pk, setprio, XCD swizzle. LDS 20416 B -> 8 blocks/CU, 32 waves/CU.
//
// NHWC xT bf16 in d_ws; K tap-major (k=tap*64+c, K=576).
// MFMA layouts (m89/m120-verified): A[m=lane&15][k=(lane>>4)*8+j];
// B[k=(lane>>4)*8+j][n=lane&15]; D: n=lane&15, m=(lane>>4)*4+reg.
// B-frags pre-swizzled: Wb[kb][nt][lane][j] = W[k=kb*32+(lane>>4)*8+j][n=nt*16+(lane&15)].

#define HH 128
#define WW 128
#define KP2 200   // samp row stride (ushorts): 192 data + 8 pad; 400B rows (16B-aligned)

typedef __attribute__((ext_vector_type(8))) short bf16x8;
typedef __attribute__((ext_vector_type(4))) float f32x4;

__device__ __forceinline__ unsigned short f2bf(float f) {
    union { __hip_bfloat16 b; unsigned short u; } cv;
    cv.b = __float2bfloat16(f);
    return cv.u;
}
__device__ __forceinline__ float bf2f(unsigned short u) {
    union { unsigned int i; float f; } cv;
    cv.i = ((unsigned int)u) << 16;
    return cv.f;
}
// RNE-pack two f32 into one dword of 2xbf16 (lo=a, hi=b).
__device__ __forceinline__ unsigned int cvt_pk_bf16(float a, float b) {
    unsigned int r;
    asm("v_cvt_pk_bf16_f32 %0, %1, %2" : "=v"(r) : "v"(a), "v"(b));
    return r;
}

// ws layout (ushort):
//   [0, 36864)          WbM [18][4][64][8]
//   [36864, 55296)      WbO [18][2][64][8]
//   [55296, +4.19M)     xT  [4][128][128][64] bf16 NHWC
#define WBM_ELEMS 36864
#define WBO_ELEMS 18432
#define XT_OFF    55296

// ------- transpose (NCHW fp32 -> NHWC bf16) + weight swizzle, merged -------
__global__ __launch_bounds__(256) void transpose_kernel(
    const float* __restrict__ x,
    const float* __restrict__ w_off,
    const float* __restrict__ wgt,
    unsigned short* __restrict__ ws)
{
    __shared__ float tile[64 * 65];
    const int tid = threadIdx.x;

    // --- weight swizzle (first 55296 global threads) ---
    {
        int t = blockIdx.x * 256 + tid;
        if (t < WBM_ELEMS) {
            int j = t & 7, lane = (t >> 3) & 63, nt = (t >> 9) & 3, kb = t >> 11;
            int k = kb * 32 + ((lane >> 4) << 3) + j;
            int n = nt * 16 + (lane & 15);
            int tap = k >> 6, c = k & 63;
            ws[t] = f2bf(wgt[n * 576 + c * 9 + tap]);
        } else if (t < WBM_ELEMS + WBO_ELEMS) {
            int t2 = t - WBM_ELEMS;
            int j = t2 & 7, lane = (t2 >> 3) & 63, nt = (t2 >> 9) & 1, kb = t2 >> 10;
            int k = kb * 32 + ((lane >> 4) << 3) + j;
            int n = nt * 16 + (lane & 15);
            int tap = k >> 6, c = k & 63;
            ws[t] = (n < 27) ? f2bf(w_off[n * 576 + c * 9 + tap]) : (unsigned short)0;
        }
    }

    // --- transpose ---
    const int bb  = blockIdx.x >> 8;
    const int hw0 = (blockIdx.x & 255) << 6;
    const float* xb = x + ((size_t)bb << 20);
#pragma unroll
    for (int it = 0; it < 16; ++it) {
        int idx = it * 256 + tid;
        int c = idx >> 6, i = idx & 63;
        tile[c * 65 + i] = xb[(c << 14) + hw0 + i];   // coalesced in i
    }
    __syncthreads();
    unsigned int* xtb = (unsigned int*)(ws + XT_OFF) + ((size_t)bb << 19);
#pragma unroll
    for (int it = 0; it < 8; ++it) {
        int idx = it * 256 + tid;
        int i = idx >> 5, c2 = idx & 31;
        xtb[(size_t)(hw0 + i) * 32 + c2] =
            cvt_pk_bf16(tile[(2 * c2) * 65 + i], tile[(2 * c2 + 1) * 65 + i]);
    }
}

// ---------------- main kernel: 4 waves / 32 pixels per block ----------------
__global__ __launch_bounds__(256, 8) void DeformConv_14568529068723_kernel(
    const float* __restrict__ b_off,
    const float* __restrict__ bias,
    const float* __restrict__ gamma,
    const float* __restrict__ beta,
    const float* __restrict__ rmean,
    const float* __restrict__ rvar,
    const unsigned short* __restrict__ ws,
    float* __restrict__ out)
{
    // samp: [32 px][KP2] bf16 staging; aliased by rb rows 0-1 (offset-conv
    // input rows, dead before offs) and offs f32[27][32].
    __shared__ __align__(16) unsigned short samp[32 * KP2];  // 12800 B
    __shared__ __align__(16) float eL[4][9][32]; // bilinear weights; aliased by rb row 2
    __shared__ int   oL[2][9][32];       // row0/row1 base element offsets
    __shared__ float sbuf[176];          // 0-63 scale, 64-127 bias2, 128-154 b_off

    const int tid  = threadIdx.x;        // 0..255
    const int wv   = tid >> 6;           // wave id
    const int lane = tid & 63;
    const int px16 = lane & 15;          // MFMA m-lane
    const int cg   = lane >> 4;          // MFMA k-quad
    const int c8   = tid & 7;            // staging: channel group (8 ch)
    const int pxq  = tid >> 3;           // staging: px slot (all 32 covered)

    if (tid < 64) {
        float sc = gamma[tid] * __frsqrt_rn(rvar[tid] + 1e-5f);
        sbuf[tid] = sc;
        sbuf[64 + tid] = (bias[tid] - rmean[tid]) * sc + beta[tid];
        if (tid < 27) sbuf[128 + tid] = b_off[tid];
    }
    // (no barrier here: the post-staging barrier below precedes all sbuf reads)

    // XCD-chunked bijective swizzle (2048 blocks, 8 XCDs, 256 blocks/XCD).
    const int bid = blockIdx.x;
    const int swz = ((bid & 7) << 8) + (bid >> 3);
    const int p0   = swz * 32;
    const int b    = p0 >> 14;
    const int rem0 = p0 & 16383;
    const int h    = rem0 >> 7;
    const int w0   = rem0 & 127;
    const unsigned short* xt = ws + XT_OFF + ((size_t)b << 20);

    const bf16x8* WbM = (const bf16x8*)ws;
    const bf16x8* WbO = (const bf16x8*)(ws + WBM_ELEMS);

    // rb: 3 rows (h-1,h,h+1) x [34 cols][64 ch] bf16, XOR-swizzled by col&7
    // (breaks the 128B-stride bank pattern). Rows 0-1 live in samp
    // (2x2176 = 4352 of 6400 ushorts), row 2 in the eL alias (2176 <= 2304).
    // Both regions are dead until after the offset-MFMA barrier.
    unsigned short* rbrow2 = (unsigned short*)eL;

    // ---- stage all 3 rows in one batch: 816 uint4 loads ----
    for (int i = tid; i < 816; i += 256) {
        int j = i / 272;                 // row 0..2
        int rem = i - j * 272;
        int cc = rem >> 3, c8i = rem & 7;
        int yy = h + j - 1;
        int gx = w0 - 1 + cc;
        bool ok = (yy >= 0) & (yy < HH) & (gx >= 0) & (gx < WW);
        int pos = min(max(yy, 0), HH - 1) * WW + min(max(gx, 0), WW - 1);
        uint4 v = *(const uint4*)(xt + pos * 64 + (c8i << 3));
        if (!ok) { v.x = 0u; v.y = 0u; v.z = 0u; v.w = 0u; }
        unsigned short* rb = (j < 2) ? &samp[j * 2176] : rbrow2;
        *(uint4*)&rb[cc * 64 + ((c8i ^ (cc & 7)) << 3)] = v;
    }
    __syncthreads();

    // ================= offset conv via MFMA (18 steps, 4-way wave split) ==========
    // wave wv -> (ocO = wv&1, mtO = wv>>1): one WbO N-frag, one M-tile each.
    const int ocO = wv & 1;
    const int mtO = wv >> 1;
    f32x4 accO = (f32x4){0.f, 0.f, 0.f, 0.f};

    {
        __builtin_amdgcn_s_setprio(1);
#pragma unroll
        for (int chk = 0; chk < 3; ++chk) {
            const unsigned short* rb = (chk < 2) ? &samp[chk * 2176]
                                                 : (const unsigned short*)rbrow2;
#pragma unroll
            for (int st = 0; st < 6; ++st) {
                int kb = chk * 6 + st;
                int tl = st >> 1;            // tap column within row
                int g0 = (st & 1) * 4 + cg;  // 8-ch group index
                bf16x8 bO = WbO[(kb * 2 + ocO) * 64 + lane];
                int col = mtO * 16 + px16 + tl;
                bf16x8 af = *(const bf16x8*)&rb[(col * 64) + (((g0 ^ (col & 7)) << 3))];
                accO = __builtin_amdgcn_mfma_f32_16x16x32_bf16(af, bO, accO, 0, 0, 0);
            }
        }
        __builtin_amdgcn_s_setprio(0);
    }
    __syncthreads();   // rb reads done; samp/eL may be overwritten below

    // D -> offs[oc][px32] (aliased into samp), + bias, sigmoid masks.
    float* offs = (float*)samp;          // f32[27][32] = 3456 B
    {
        int n0 = ocO * 16 + (lane & 15);
        int mB = cg * 4;
        if (n0 < 27) {
            float bo = sbuf[128 + n0];
#pragma unroll
            for (int r = 0; r < 4; ++r) {
                int pxc = mtO * 16 + mB + r;
                float vv = accO[r] + bo;
                if (n0 >= 18) vv = 1.0f / (1.0f + __expf(-vv));
                offs[n0 * 32 + pxc] = vv;
            }
        }
    }
    __syncthreads();

    // ========= bilinear setup per (px,tap) -> LDS (corner-select folded into e-weights) =========
    // (writes eL -> rb row 2 dead from here on)
#pragma unroll
    for (int base = 0; base < 288; base += 256) {
        int idx = base + tid;
        if (idx < 288) {
            int px = idx & 31, tap = idx >> 5;
            float o1 = offs[(2 * tap) * 32 + px];
            float o2 = offs[(2 * tap + 1) * 32 + px];
            float m  = offs[(18 + tap) * 32 + px];
            float py  = (float)(h + tap / 3 - 1) + o1;
            float pxf = (float)(w0 + px + tap % 3 - 1) + o2;
            float y0f = floorf(py), x0f = floorf(pxf);
            float dy = py - y0f, dx = pxf - x0f;
            int y0 = (int)y0f, x0 = (int)x0f;
            int y1 = y0 + 1, x1 = x0 + 1;
            int yc0 = min(max(y0, 0), HH - 1), yc1 = min(max(y1, 0), HH - 1);
            int xc0 = min(max(x0, 0), WW - 1), xc1 = min(max(x1, 0), WW - 1);
            float vy0 = (y0 >= 0 && y0 < HH) ? 1.0f : 0.0f;
            float vy1 = (y1 >= 0 && y1 < HH) ? 1.0f : 0.0f;
            float vx0 = (x0 >= 0 && x0 < WW) ? 1.0f : 0.0f;
            float vx1 = (x1 >= 0 && x1 < WW) ? 1.0f : 0.0f;
            float c00 = (1.0f - dy) * (1.0f - dx) * m * vy0 * vx0;
            float c01 = (1.0f - dy) * dx * m * vy0 * vx1;
            float c10 = dy * (1.0f - dx) * m * vy1 * vx0;
            float c11 = dy * dx * m * vy1 * vx1;
            int bx = min(xc0, WW - 2);        // column pair [bx, bx+1] in-bounds
            bool s0 = (xc0 != bx), s1 = (xc1 != bx);
            eL[0][tap][px] = (s0 ? 0.f : c00) + (s1 ? 0.f : c01);
            eL[1][tap][px] = (s0 ? c00 : 0.f) + (s1 ? c01 : 0.f);
            eL[2][tap][px] = (s0 ? 0.f : c10) + (s1 ? 0.f : c11);
            eL[3][tap][px] = (s0 ? c10 : 0.f) + (s1 ? c11 : 0.f);
            oL[0][tap][px] = (yc0 * WW + bx) * 64;
            oL[1][tap][px] = (yc1 * WW + bx) * 64;
        }
    }
    __syncthreads();

    // ================= main conv via MFMA (3 chunks of 3 taps) =================
    // wave wv owns N-tile nt=wv, computes both M-tiles -> weights loaded once.
    f32x4 acc[2];
#pragma unroll
    for (int mt = 0; mt < 2; ++mt) acc[mt] = (f32x4){0.f, 0.f, 0.f, 0.f};

    for (int chk = 0; chk < 3; ++chk) {
#pragma unroll
        for (int tl = 0; tl < 3; ++tl) {
            int tap = chk * 3 + tl;
            int o0 = oL[0][tap][pxq], o1r = oL[1][tap][pxq];
            float e0 = eL[0][tap][pxq], e1 = eL[1][tap][pxq];
            float e2 = eL[2][tap][pxq], e3 = eL[3][tap][pxq];
            uint4 a0 = *(const uint4*)(xt + o0 + (c8 << 3));
            uint4 a1 = *(const uint4*)(xt + o0 + 64 + (c8 << 3));
            uint4 b0 = *(const uint4*)(xt + o1r + (c8 << 3));
            uint4 b1 = *(const uint4*)(xt + o1r + 64 + (c8 << 3));
            const unsigned int* pa0 = (const unsigned int*)&a0;
            const unsigned int* pa1 = (const unsigned int*)&a1;
            const unsigned int* pb0 = (const unsigned int*)&b0;
            const unsigned int* pb1 = (const unsigned int*)&b1;
            uint4 pk;
            unsigned int* pp = (unsigned int*)&pk;
#pragma unroll
            for (int q = 0; q < 4; ++q) {
                float lo = e0 * bf2f((unsigned short)(pa0[q] & 0xffff))
                         + e1 * bf2f((unsigned short)(pa1[q] & 0xffff))
                         + e2 * bf2f((unsigned short)(pb0[q] & 0xffff))
                         + e3 * bf2f((unsigned short)(pb1[q] & 0xffff));
                float hi = e0 * bf2f((unsigned short)(pa0[q] >> 16))
                         + e1 * bf2f((unsigned short)(pa1[q] >> 16))
                         + e2 * bf2f((unsigned short)(pb0[q] >> 16))
                         + e3 * bf2f((unsigned short)(pb1[q] >> 16));
                pp[q] = cvt_pk_bf16(lo, hi);
            }
            *(uint4*)&samp[pxq * KP2 + tl * 64 + (c8 << 3)] = pk;
        }
        __syncthreads();
        __builtin_amdgcn_s_setprio(1);
#pragma unroll
        for (int st = 0; st < 6; ++st) {
            int kb = chk * 6 + st;
            bf16x8 bf = WbM[(kb * 4 + wv) * 64 + lane];
            bf16x8 af0 = *(const bf16x8*)&samp[px16 * KP2 + st * 32 + (cg << 3)];
            bf16x8 af1 = *(const bf16x8*)&samp[(16 + px16) * KP2 + st * 32 + (cg << 3)];
            acc[0] = __builtin_amdgcn_mfma_f32_16x16x32_bf16(af0, bf, acc[0], 0, 0, 0);
            acc[1] = __builtin_amdgcn_mfma_f32_16x16x32_bf16(af1, bf, acc[1], 0, 0, 0);
        }
        __builtin_amdgcn_s_setprio(0);
        if (chk < 2) __syncthreads();    // chunk 2: no LDS writes follow
    }

    // ================= epilogue: BN + ReLU in regs, direct float4 stores ==========
    // D-layout: thread holds px = mt*16 + cg*4 + r (consecutive in r) for
    // o = wv*16 + n0 -> float4 store; cg-clusters cover 64B lines.
    {
        int o = wv * 16 + (lane & 15);
        float sc = sbuf[o], b2 = sbuf[64 + o];
        float* op = out + (((size_t)(b * 64 + o)) << 14) + rem0;
#pragma unroll
        for (int mt = 0; mt < 2; ++mt) {
            f32x4 st;
#pragma unroll
            for (int r = 0; r < 4; ++r)
                st[r] = fmaxf(fmaf(acc[mt][r], sc, b2), 0.0f);
            *(f32x4*)(op + mt * 16 + cg * 4) = st;
        }
    }
}

extern "C" void kernel_launch(void* const* d_in, const int* in_sizes, int n_in,
                              void* d_out, int out_size, void* d_ws, size_t ws_size,
                              hipStream_t stream) {
    (void)in_sizes; (void)n_in; (void)ws_size; (void)out_size;
    const float* x     = (const float*)d_in[0];
    const float* w_off = (const float*)d_in[1];
    const float* b_off = (const float*)d_in[2];
    const float* wgt   = (const float*)d_in[3];
    const float* bias  = (const float*)d_in[4];
    const float* gamma = (const float*)d_in[5];
    const float* beta  = (const float*)d_in[6];
    const float* rmean = (const float*)d_in[7];
    const float* rvar  = (const float*)d_in[8];
    unsigned short* wsB = (unsigned short*)d_ws;
    float* outp = (float*)d_out;

    transpose_kernel<<<dim3(1024), dim3(256), 0, stream>>>(x, w_off, wgt, wsB);
    // 65536 px / 32 per block = 2048 blocks of 256 threads (4 waves each)
    DeformConv_14568529068723_kernel<<<dim3(2048), dim3(256), 0, stream>>>(
        b_off, bias, gamma, beta, rmean, rvar, wsB, outp);
}

// Round 11
// 109.391 us; speedup vs baseline: 1.0044x; 1.0044x over previous
//
#include <hip/hip_runtime.h>
#include <hip/hip_bf16.h>

// DCN v2 (modulated deformable 3x3 conv) + BN(eval) + ReLU, fused, MFMA.
// B=4, C=64, O=64, H=W=128. fp32 in/out; bf16 MFMA 16x16x32, fp32 accum.
//
// R24: decompose R23. R23 bundled (a) offset-conv 4-way split, (b) direct
// -store epilogue, (c) dead-barrier drop -> +1.25us net. Post-mortem found
// (a)'s cost was mis-estimated 60x: 4-way split doubles WbO traffic
// (36->72 KB/block = +74 MB, +13% of L2 bytes) for a phase that is ~20% of
// the kernel. R24 = R22 (best, 108.62us: 2-wave offset conv) + (b) + (c)
// only: epilogue direct float4 stores (D-layout gives 4 consecutive px per
// acc; cg clusters cover 64B lines; deletes dT transpose + 2 barriers +
// 16 KB/block LDS traffic) and chunk-2 trailing barrier dropped.
// Base kept: 4-wave/32-px, launch_bounds(256,8) -> 32 waves/CU HW max,
// single-batch 3-row stage, cvt_pk, setprio, XCD swizzle. LDS 20416 B.
// Pre-commit: if >= 108.6, R22 config is the empirical optimum (scattered
// -L2 service floor) -> revert + declare roofline.
//
// NHWC xT bf16 in d_ws; K tap-major (k=tap*64+c, K=576).
// MFMA layouts (m89/m120-verified): A[m=lane&15][k=(lane>>4)*8+j];
// B[k=(lane>>4)*8+j][n=lane&15]; D: n=lane&15, m=(lane>>4)*4+reg.
// B-frags pre-swizzled: Wb[kb][nt][lane][j] = W[k=kb*32+(lane>>4)*8+j][n=nt*16+(lane&15)].

#define HH 128
#define WW 128
#define KP2 200   // samp row stride (ushorts): 192 data + 8 pad; 400B rows (16B-aligned)

typedef __attribute__((ext_vector_type(8))) short bf16x8;
typedef __attribute__((ext_vector_type(4))) float f32x4;

__device__ __forceinline__ unsigned short f2bf(float f) {
    union { __hip_bfloat16 b; unsigned short u; } cv;
    cv.b = __float2bfloat16(f);
    return cv.u;
}
__device__ __forceinline__ float bf2f(unsigned short u) {
    union { unsigned int i; float f; } cv;
    cv.i = ((unsigned int)u) << 16;
    return cv.f;
}
// RNE-pack two f32 into one dword of 2xbf16 (lo=a, hi=b).
__device__ __forceinline__ unsigned int cvt_pk_bf16(float a, float b) {
    unsigned int r;
    asm("v_cvt_pk_bf16_f32 %0, %1, %2" : "=v"(r) : "v"(a), "v"(b));
    return r;
}

// ws layout (ushort):
//   [0, 36864)          WbM [18][4][64][8]
//   [36864, 55296)      WbO [18][2][64][8]
//   [55296, +4.19M)     xT  [4][128][128][64] bf16 NHWC
#define WBM_ELEMS 36864
#define WBO_ELEMS 18432
#define XT_OFF    55296

// ------- transpose (NCHW fp32 -> NHWC bf16) + weight swizzle, merged -------
__global__ __launch_bounds__(256) void transpose_kernel(
    const float* __restrict__ x,
    const float* __restrict__ w_off,
    const float* __restrict__ wgt,
    unsigned short* __restrict__ ws)
{
    __shared__ float tile[64 * 65];
    const int tid = threadIdx.x;

    // --- weight swizzle (first 55296 global threads) ---
    {
        int t = blockIdx.x * 256 + tid;
        if (t < WBM_ELEMS) {
            int j = t & 7, lane = (t >> 3) & 63, nt = (t >> 9) & 3, kb = t >> 11;
            int k = kb * 32 + ((lane >> 4) << 3) + j;
            int n = nt * 16 + (lane & 15);
            int tap = k >> 6, c = k & 63;
            ws[t] = f2bf(wgt[n * 576 + c * 9 + tap]);
        } else if (t < WBM_ELEMS + WBO_ELEMS) {
            int t2 = t - WBM_ELEMS;
            int j = t2 & 7, lane = (t2 >> 3) & 63, nt = (t2 >> 9) & 1, kb = t2 >> 10;
            int k = kb * 32 + ((lane >> 4) << 3) + j;
            int n = nt * 16 + (lane & 15);
            int tap = k >> 6, c = k & 63;
            ws[t] = (n < 27) ? f2bf(w_off[n * 576 + c * 9 + tap]) : (unsigned short)0;
        }
    }

    // --- transpose ---
    const int bb  = blockIdx.x >> 8;
    const int hw0 = (blockIdx.x & 255) << 6;
    const float* xb = x + ((size_t)bb << 20);
#pragma unroll
    for (int it = 0; it < 16; ++it) {
        int idx = it * 256 + tid;
        int c = idx >> 6, i = idx & 63;
        tile[c * 65 + i] = xb[(c << 14) + hw0 + i];   // coalesced in i
    }
    __syncthreads();
    unsigned int* xtb = (unsigned int*)(ws + XT_OFF) + ((size_t)bb << 19);
#pragma unroll
    for (int it = 0; it < 8; ++it) {
        int idx = it * 256 + tid;
        int i = idx >> 5, c2 = idx & 31;
        xtb[(size_t)(hw0 + i) * 32 + c2] =
            cvt_pk_bf16(tile[(2 * c2) * 65 + i], tile[(2 * c2 + 1) * 65 + i]);
    }
}

// ---------------- main kernel: 4 waves / 32 pixels per block ----------------
__global__ __launch_bounds__(256, 8) void DeformConv_14568529068723_kernel(
    const float* __restrict__ b_off,
    const float* __restrict__ bias,
    const float* __restrict__ gamma,
    const float* __restrict__ beta,
    const float* __restrict__ rmean,
    const float* __restrict__ rvar,
    const unsigned short* __restrict__ ws,
    float* __restrict__ out)
{
    // samp: [32 px][KP2] bf16 staging; aliased by rb rows 0-1 (offset-conv
    // input rows, dead before offs) and offs f32[27][32].
    __shared__ __align__(16) unsigned short samp[32 * KP2];  // 12800 B
    __shared__ __align__(16) float eL[4][9][32]; // bilinear weights; aliased by rb row 2
    __shared__ int   oL[2][9][32];       // row0/row1 base element offsets
    __shared__ float sbuf[176];          // 0-63 scale, 64-127 bias2, 128-154 b_off

    const int tid  = threadIdx.x;        // 0..255
    const int wv   = tid >> 6;           // wave id
    const int lane = tid & 63;
    const int px16 = lane & 15;          // MFMA m-lane
    const int cg   = lane >> 4;          // MFMA k-quad
    const int c8   = tid & 7;            // staging: channel group (8 ch)
    const int pxq  = tid >> 3;           // staging: px slot (all 32 covered)

    if (tid < 64) {
        float sc = gamma[tid] * __frsqrt_rn(rvar[tid] + 1e-5f);
        sbuf[tid] = sc;
        sbuf[64 + tid] = (bias[tid] - rmean[tid]) * sc + beta[tid];
        if (tid < 27) sbuf[128 + tid] = b_off[tid];
    }
    // (no barrier here: the post-staging barrier below precedes all sbuf reads)

    // XCD-chunked bijective swizzle (2048 blocks, 8 XCDs, 256 blocks/XCD).
    const int bid = blockIdx.x;
    const int swz = ((bid & 7) << 8) + (bid >> 3);
    const int p0   = swz * 32;
    const int b    = p0 >> 14;
    const int rem0 = p0 & 16383;
    const int h    = rem0 >> 7;
    const int w0   = rem0 & 127;
    const unsigned short* xt = ws + XT_OFF + ((size_t)b << 20);

    const bf16x8* WbM = (const bf16x8*)ws;
    const bf16x8* WbO = (const bf16x8*)(ws + WBM_ELEMS);

    // rb: 3 rows (h-1,h,h+1) x [34 cols][64 ch] bf16, XOR-swizzled by col&7
    // (breaks the 128B-stride bank pattern). Rows 0-1 live in samp
    // (2x2176 = 4352 of 6400 ushorts), row 2 in the eL alias (2176 <= 2304).
    // Both regions are dead until after the offset-MFMA barrier.
    unsigned short* rbrow2 = (unsigned short*)eL;

    // ---- stage all 3 rows in one batch: 816 uint4 loads ----
    for (int i = tid; i < 816; i += 256) {
        int j = i / 272;                 // row 0..2
        int rem = i - j * 272;
        int cc = rem >> 3, c8i = rem & 7;
        int yy = h + j - 1;
        int gx = w0 - 1 + cc;
        bool ok = (yy >= 0) & (yy < HH) & (gx >= 0) & (gx < WW);
        int pos = min(max(yy, 0), HH - 1) * WW + min(max(gx, 0), WW - 1);
        uint4 v = *(const uint4*)(xt + pos * 64 + (c8i << 3));
        if (!ok) { v.x = 0u; v.y = 0u; v.z = 0u; v.w = 0u; }
        unsigned short* rb = (j < 2) ? &samp[j * 2176] : rbrow2;
        *(uint4*)&rb[cc * 64 + ((c8i ^ (cc & 7)) << 3)] = v;
    }
    __syncthreads();

    // ================= offset conv via MFMA (18 steps, no intra barriers) ==========
    // Waves 0-1 only: wave wv = oc-frag wv, computes BOTH M-tiles.
    f32x4 accO[2];
#pragma unroll
    for (int q = 0; q < 2; ++q) accO[q] = (f32x4){0.f, 0.f, 0.f, 0.f};

    if (wv < 2) {
        __builtin_amdgcn_s_setprio(1);
#pragma unroll
        for (int chk = 0; chk < 3; ++chk) {
            const unsigned short* rb = (chk < 2) ? &samp[chk * 2176]
                                                 : (const unsigned short*)rbrow2;
#pragma unroll
            for (int st = 0; st < 6; ++st) {
                int kb = chk * 6 + st;
                int tl = st >> 1;            // tap column within row
                int g0 = (st & 1) * 4 + cg;  // 8-ch group index
                bf16x8 bO = WbO[(kb * 2 + wv) * 64 + lane];
#pragma unroll
                for (int mt = 0; mt < 2; ++mt) {
                    int col = mt * 16 + px16 + tl;
                    bf16x8 af = *(const bf16x8*)&rb[(col * 64) + (((g0 ^ (col & 7)) << 3))];
                    accO[mt] = __builtin_amdgcn_mfma_f32_16x16x32_bf16(af, bO, accO[mt], 0, 0, 0);
                }
            }
        }
        __builtin_amdgcn_s_setprio(0);
    }
    __syncthreads();   // rb reads done; samp/eL may be overwritten below

    // D -> offs[oc][px32] (aliased into samp), + bias, sigmoid masks.
    float* offs = (float*)samp;          // f32[27][32] = 3456 B
    if (wv < 2) {
        int n0 = wv * 16 + (lane & 15);
        int mB = cg * 4;
        if (n0 < 27) {
#pragma unroll
            for (int mt = 0; mt < 2; ++mt)
#pragma unroll
                for (int r = 0; r < 4; ++r) {
                    int pxc = mt * 16 + mB + r;
                    float vv = accO[mt][r] + sbuf[128 + n0];
                    if (n0 >= 18) vv = 1.0f / (1.0f + __expf(-vv));
                    offs[n0 * 32 + pxc] = vv;
                }
        }
    }
    __syncthreads();

    // ========= bilinear setup per (px,tap) -> LDS (corner-select folded into e-weights) =========
    // (writes eL -> rb row 2 dead from here on)
#pragma unroll
    for (int base = 0; base < 288; base += 256) {
        int idx = base + tid;
        if (idx < 288) {
            int px = idx & 31, tap = idx >> 5;
            float o1 = offs[(2 * tap) * 32 + px];
            float o2 = offs[(2 * tap + 1) * 32 + px];
            float m  = offs[(18 + tap) * 32 + px];
            float py  = (float)(h + tap / 3 - 1) + o1;
            float pxf = (float)(w0 + px + tap % 3 - 1) + o2;
            float y0f = floorf(py), x0f = floorf(pxf);
            float dy = py - y0f, dx = pxf - x0f;
            int y0 = (int)y0f, x0 = (int)x0f;
            int y1 = y0 + 1, x1 = x0 + 1;
            int yc0 = min(max(y0, 0), HH - 1), yc1 = min(max(y1, 0), HH - 1);
            int xc0 = min(max(x0, 0), WW - 1), xc1 = min(max(x1, 0), WW - 1);
            float vy0 = (y0 >= 0 && y0 < HH) ? 1.0f : 0.0f;
            float vy1 = (y1 >= 0 && y1 < HH) ? 1.0f : 0.0f;
            float vx0 = (x0 >= 0 && x0 < WW) ? 1.0f : 0.0f;
            float vx1 = (x1 >= 0 && x1 < WW) ? 1.0f : 0.0f;
            float c00 = (1.0f - dy) * (1.0f - dx) * m * vy0 * vx0;
            float c01 = (1.0f - dy) * dx * m * vy0 * vx1;
            float c10 = dy * (1.0f - dx) * m * vy1 * vx0;
            float c11 = dy * dx * m * vy1 * vx1;
            int bx = min(xc0, WW - 2);        // column pair [bx, bx+1] in-bounds
            bool s0 = (xc0 != bx), s1 = (xc1 != bx);
            eL[0][tap][px] = (s0 ? 0.f : c00) + (s1 ? 0.f : c01);
            eL[1][tap][px] = (s0 ? c00 : 0.f) + (s1 ? c01 : 0.f);
            eL[2][tap][px] = (s0 ? 0.f : c10) + (s1 ? 0.f : c11);
            eL[3][tap][px] = (s0 ? c10 : 0.f) + (s1 ? c11 : 0.f);
            oL[0][tap][px] = (yc0 * WW + bx) * 64;
            oL[1][tap][px] = (yc1 * WW + bx) * 64;
        }
    }
    __syncthreads();

    // ================= main conv via MFMA (3 chunks of 3 taps) =================
    // wave wv owns N-tile nt=wv, computes both M-tiles -> weights loaded once.
    f32x4 acc[2];
#pragma unroll
    for (int mt = 0; mt < 2; ++mt) acc[mt] = (f32x4){0.f, 0.f, 0.f, 0.f};

    for (int chk = 0; chk < 3; ++chk) {
#pragma unroll
        for (int tl = 0; tl < 3; ++tl) {
            int tap = chk * 3 + tl;
            int o0 = oL[0][tap][pxq], o1r = oL[1][tap][pxq];
            float e0 = eL[0][tap][pxq], e1 = eL[1][tap][pxq];
            float e2 = eL[2][tap][pxq], e3 = eL[3][tap][pxq];
            uint4 a0 = *(const uint4*)(xt + o0 + (c8 << 3));
            uint4 a1 = *(const uint4*)(xt + o0 + 64 + (c8 << 3));
            uint4 b0 = *(const uint4*)(xt + o1r + (c8 << 3));
            uint4 b1 = *(const uint4*)(xt + o1r + 64 + (c8 << 3));
            const unsigned int* pa0 = (const unsigned int*)&a0;
            const unsigned int* pa1 = (const unsigned int*)&a1;
            const unsigned int* pb0 = (const unsigned int*)&b0;
            const unsigned int* pb1 = (const unsigned int*)&b1;
            uint4 pk;
            unsigned int* pp = (unsigned int*)&pk;
#pragma unroll
            for (int q = 0; q < 4; ++q) {
                float lo = e0 * bf2f((unsigned short)(pa0[q] & 0xffff))
                         + e1 * bf2f((unsigned short)(pa1[q] & 0xffff))
                         + e2 * bf2f((unsigned short)(pb0[q] & 0xffff))
                         + e3 * bf2f((unsigned short)(pb1[q] & 0xffff));
                float hi = e0 * bf2f((unsigned short)(pa0[q] >> 16))
                         + e1 * bf2f((unsigned short)(pa1[q] >> 16))
                         + e2 * bf2f((unsigned short)(pb0[q] >> 16))
                         + e3 * bf2f((unsigned short)(pb1[q] >> 16));
                pp[q] = cvt_pk_bf16(lo, hi);
            }
            *(uint4*)&samp[pxq * KP2 + tl * 64 + (c8 << 3)] = pk;
        }
        __syncthreads();
        __builtin_amdgcn_s_setprio(1);
#pragma unroll
        for (int st = 0; st < 6; ++st) {
            int kb = chk * 6 + st;
            bf16x8 bf = WbM[(kb * 4 + wv) * 64 + lane];
            bf16x8 af0 = *(const bf16x8*)&samp[px16 * KP2 + st * 32 + (cg << 3)];
            bf16x8 af1 = *(const bf16x8*)&samp[(16 + px16) * KP2 + st * 32 + (cg << 3)];
            acc[0] = __builtin_amdgcn_mfma_f32_16x16x32_bf16(af0, bf, acc[0], 0, 0, 0);
            acc[1] = __builtin_amdgcn_mfma_f32_16x16x32_bf16(af1, bf, acc[1], 0, 0, 0);
        }
        __builtin_amdgcn_s_setprio(0);
        if (chk < 2) __syncthreads();    // chunk 2: no LDS writes follow
    }

    // ================= epilogue: BN + ReLU in regs, direct float4 stores ==========
    // D-layout: thread holds px = mt*16 + cg*4 + r (consecutive in r) for
    // o = wv*16 + n0 -> float4 store; cg-clusters cover 64B lines.
    {
        int o = wv * 16 + (lane & 15);
        float sc = sbuf[o], b2 = sbuf[64 + o];
        float* op = out + (((size_t)(b * 64 + o)) << 14) + rem0;
#pragma unroll
        for (int mt = 0; mt < 2; ++mt) {
            f32x4 st;
#pragma unroll
            for (int r = 0; r < 4; ++r)
                st[r] = fmaxf(fmaf(acc[mt][r], sc, b2), 0.0f);
            *(f32x4*)(op + mt * 16 + cg * 4) = st;
        }
    }
}

extern "C" void kernel_launch(void* const* d_in, const int* in_sizes, int n_in,
                              void* d_out, int out_size, void* d_ws, size_t ws_size,
                              hipStream_t stream) {
    (void)in_sizes; (void)n_in; (void)ws_size; (void)out_size;
    const float* x     = (const float*)d_in[0];
    const float* w_off = (const float*)d_in[1];
    const float* b_off = (const float*)d_in[2];
    const float* wgt   = (const float*)d_in[3];
    const float* bias  = (const float*)d_in[4];
    const float* gamma = (const float*)d_in[5];
    const float* beta  = (const float*)d_in[6];
    const float* rmean = (const float*)d_in[7];
    const float* rvar  = (const float*)d_in[8];
    unsigned short* wsB = (unsigned short*)d_ws;
    float* outp = (float*)d_out;

    transpose_kernel<<<dim3(1024), dim3(256), 0, stream>>>(x, w_off, wgt, wsB);
    // 65536 px / 32 per block = 2048 blocks of 256 threads (4 waves each)
    DeformConv_14568529068723_kernel<<<dim3(2048), dim3(256), 0, stream>>>(
        b_off, bias, gamma, beta, rmean, rvar, wsB, outp);
}

// Round 12
// 107.520 us; speedup vs baseline: 1.0219x; 1.0174x over previous
//
#include <hip/hip_runtime.h>
#include <hip/hip_bf16.h>

// DCN v2 (modulated deformable 3x3 conv) + BN(eval) + ReLU, fused, MFMA.
// B=4, C=64, O=64, H=W=128. fp32 in/out; bf16 MFMA 16x16x32, fp32 accum.
//
// R25 = exact R22 revert (best: 108.62 us). R23/R24 decomposition refuted
// both candidate changes: (a) offset-conv 4-way split doubles WbO traffic
// (+74 MB) -> +1 us; (b) direct-store epilogue de-coalesces stores (16B
// segments vs dT's 128B rows) -> +0.8 us. R22 is the empirical optimum:
//   occupancy at HW max (R21: launch_bounds(256,8) -> 64 VGPR, 32 waves/CU),
//   VALU flat (R19), traffic response flattened (R16-R18), structural
//   pivots regress (R18 64-px, R20 LDS-window), sync captured (R22).
// Main kernel ~27 us vs ~24-25 us scattered-L2 service floor estimate.
//
// Config: 4-wave/32-px blocks; single-batch 3-row stage into samp/eL
// aliases (XOR-swizzled); 2-wave offset conv (WbO-deduped, both M-tiles);
// bilinear setup w/ corner-select folded into e-weights; 3-chunk main conv
// (wave = N-tile, weights loaded once, 2 M-tiles); dT-transpose epilogue
// for 128B-coalesced stores; cvt_pk packing; setprio around MFMA; XCD
// swizzle. LDS 20416 B -> 8 blocks/CU.
//
// NHWC xT bf16 in d_ws; K tap-major (k=tap*64+c, K=576).
// MFMA layouts (m89/m120-verified): A[m=lane&15][k=(lane>>4)*8+j];
// B[k=(lane>>4)*8+j][n=lane&15]; D: n=lane&15, m=(lane>>4)*4+reg.
// B-frags pre-swizzled: Wb[kb][nt][lane][j] = W[k=kb*32+(lane>>4)*8+j][n=nt*16+(lane&15)].

#define HH 128
#define WW 128
#define KP2 200   // samp row stride (ushorts): 192 data + 8 pad; 400B rows (16B-aligned)

typedef __attribute__((ext_vector_type(8))) short bf16x8;
typedef __attribute__((ext_vector_type(4))) float f32x4;

__device__ __forceinline__ unsigned short f2bf(float f) {
    union { __hip_bfloat16 b; unsigned short u; } cv;
    cv.b = __float2bfloat16(f);
    return cv.u;
}
__device__ __forceinline__ float bf2f(unsigned short u) {
    union { unsigned int i; float f; } cv;
    cv.i = ((unsigned int)u) << 16;
    return cv.f;
}
// RNE-pack two f32 into one dword of 2xbf16 (lo=a, hi=b).
__device__ __forceinline__ unsigned int cvt_pk_bf16(float a, float b) {
    unsigned int r;
    asm("v_cvt_pk_bf16_f32 %0, %1, %2" : "=v"(r) : "v"(a), "v"(b));
    return r;
}

// ws layout (ushort):
//   [0, 36864)          WbM [18][4][64][8]
//   [36864, 55296)      WbO [18][2][64][8]
//   [55296, +4.19M)     xT  [4][128][128][64] bf16 NHWC
#define WBM_ELEMS 36864
#define WBO_ELEMS 18432
#define XT_OFF    55296

// ------- transpose (NCHW fp32 -> NHWC bf16) + weight swizzle, merged -------
__global__ __launch_bounds__(256) void transpose_kernel(
    const float* __restrict__ x,
    const float* __restrict__ w_off,
    const float* __restrict__ wgt,
    unsigned short* __restrict__ ws)
{
    __shared__ float tile[64 * 65];
    const int tid = threadIdx.x;

    // --- weight swizzle (first 55296 global threads) ---
    {
        int t = blockIdx.x * 256 + tid;
        if (t < WBM_ELEMS) {
            int j = t & 7, lane = (t >> 3) & 63, nt = (t >> 9) & 3, kb = t >> 11;
            int k = kb * 32 + ((lane >> 4) << 3) + j;
            int n = nt * 16 + (lane & 15);
            int tap = k >> 6, c = k & 63;
            ws[t] = f2bf(wgt[n * 576 + c * 9 + tap]);
        } else if (t < WBM_ELEMS + WBO_ELEMS) {
            int t2 = t - WBM_ELEMS;
            int j = t2 & 7, lane = (t2 >> 3) & 63, nt = (t2 >> 9) & 1, kb = t2 >> 10;
            int k = kb * 32 + ((lane >> 4) << 3) + j;
            int n = nt * 16 + (lane & 15);
            int tap = k >> 6, c = k & 63;
            ws[t] = (n < 27) ? f2bf(w_off[n * 576 + c * 9 + tap]) : (unsigned short)0;
        }
    }

    // --- transpose ---
    const int bb  = blockIdx.x >> 8;
    const int hw0 = (blockIdx.x & 255) << 6;
    const float* xb = x + ((size_t)bb << 20);
#pragma unroll
    for (int it = 0; it < 16; ++it) {
        int idx = it * 256 + tid;
        int c = idx >> 6, i = idx & 63;
        tile[c * 65 + i] = xb[(c << 14) + hw0 + i];   // coalesced in i
    }
    __syncthreads();
    unsigned int* xtb = (unsigned int*)(ws + XT_OFF) + ((size_t)bb << 19);
#pragma unroll
    for (int it = 0; it < 8; ++it) {
        int idx = it * 256 + tid;
        int i = idx >> 5, c2 = idx & 31;
        xtb[(size_t)(hw0 + i) * 32 + c2] =
            cvt_pk_bf16(tile[(2 * c2) * 65 + i], tile[(2 * c2 + 1) * 65 + i]);
    }
}

// ---------------- main kernel: 4 waves / 32 pixels per block ----------------
__global__ __launch_bounds__(256, 8) void DeformConv_14568529068723_kernel(
    const float* __restrict__ b_off,
    const float* __restrict__ bias,
    const float* __restrict__ gamma,
    const float* __restrict__ beta,
    const float* __restrict__ rmean,
    const float* __restrict__ rvar,
    const unsigned short* __restrict__ ws,
    float* __restrict__ out)
{
    // samp: [32 px][KP2] bf16 staging; aliased by rb rows 0-1 (offset-conv
    // input rows, dead before offs), offs f32[27][32], and dT (epilogue).
    __shared__ __align__(16) unsigned short samp[32 * KP2];  // 12800 B
    __shared__ __align__(16) float eL[4][9][32]; // bilinear weights; aliased by rb row 2
    __shared__ int   oL[2][9][32];       // row0/row1 base element offsets
    __shared__ float sbuf[176];          // 0-63 scale, 64-127 bias2, 128-154 b_off

    const int tid  = threadIdx.x;        // 0..255
    const int wv   = tid >> 6;           // wave id
    const int lane = tid & 63;
    const int px16 = lane & 15;          // MFMA m-lane
    const int cg   = lane >> 4;          // MFMA k-quad
    const int c8   = tid & 7;            // staging: channel group (8 ch)
    const int pxq  = tid >> 3;           // staging: px slot (all 32 covered)

    if (tid < 64) {
        float sc = gamma[tid] * __frsqrt_rn(rvar[tid] + 1e-5f);
        sbuf[tid] = sc;
        sbuf[64 + tid] = (bias[tid] - rmean[tid]) * sc + beta[tid];
        if (tid < 27) sbuf[128 + tid] = b_off[tid];
    }
    // (no barrier here: the post-staging barrier below precedes all sbuf reads)

    // XCD-chunked bijective swizzle (2048 blocks, 8 XCDs, 256 blocks/XCD).
    const int bid = blockIdx.x;
    const int swz = ((bid & 7) << 8) + (bid >> 3);
    const int p0   = swz * 32;
    const int b    = p0 >> 14;
    const int rem0 = p0 & 16383;
    const int h    = rem0 >> 7;
    const int w0   = rem0 & 127;
    const unsigned short* xt = ws + XT_OFF + ((size_t)b << 20);

    const bf16x8* WbM = (const bf16x8*)ws;
    const bf16x8* WbO = (const bf16x8*)(ws + WBM_ELEMS);

    // rb: 3 rows (h-1,h,h+1) x [34 cols][64 ch] bf16, XOR-swizzled by col&7
    // (breaks the 128B-stride bank pattern). Rows 0-1 live in samp
    // (2x2176 = 4352 of 6400 ushorts), row 2 in the eL alias (2176 <= 2304).
    // Both regions are dead until after the offset-MFMA barrier.
    unsigned short* rbrow2 = (unsigned short*)eL;

    // ---- stage all 3 rows in one batch: 816 uint4 loads ----
    for (int i = tid; i < 816; i += 256) {
        int j = i / 272;                 // row 0..2
        int rem = i - j * 272;
        int cc = rem >> 3, c8i = rem & 7;
        int yy = h + j - 1;
        int gx = w0 - 1 + cc;
        bool ok = (yy >= 0) & (yy < HH) & (gx >= 0) & (gx < WW);
        int pos = min(max(yy, 0), HH - 1) * WW + min(max(gx, 0), WW - 1);
        uint4 v = *(const uint4*)(xt + pos * 64 + (c8i << 3));
        if (!ok) { v.x = 0u; v.y = 0u; v.z = 0u; v.w = 0u; }
        unsigned short* rb = (j < 2) ? &samp[j * 2176] : rbrow2;
        *(uint4*)&rb[cc * 64 + ((c8i ^ (cc & 7)) << 3)] = v;
    }
    __syncthreads();

    // ================= offset conv via MFMA (18 steps, no intra barriers) ==========
    // Waves 0-1 only: wave wv = oc-frag wv, computes BOTH M-tiles.
    f32x4 accO[2];
#pragma unroll
    for (int q = 0; q < 2; ++q) accO[q] = (f32x4){0.f, 0.f, 0.f, 0.f};

    if (wv < 2) {
        __builtin_amdgcn_s_setprio(1);
#pragma unroll
        for (int chk = 0; chk < 3; ++chk) {
            const unsigned short* rb = (chk < 2) ? &samp[chk * 2176]
                                                 : (const unsigned short*)rbrow2;
#pragma unroll
            for (int st = 0; st < 6; ++st) {
                int kb = chk * 6 + st;
                int tl = st >> 1;            // tap column within row
                int g0 = (st & 1) * 4 + cg;  // 8-ch group index
                bf16x8 bO = WbO[(kb * 2 + wv) * 64 + lane];
#pragma unroll
                for (int mt = 0; mt < 2; ++mt) {
                    int col = mt * 16 + px16 + tl;
                    bf16x8 af = *(const bf16x8*)&rb[(col * 64) + (((g0 ^ (col & 7)) << 3))];
                    accO[mt] = __builtin_amdgcn_mfma_f32_16x16x32_bf16(af, bO, accO[mt], 0, 0, 0);
                }
            }
        }
        __builtin_amdgcn_s_setprio(0);
    }
    __syncthreads();   // rb reads done; samp/eL may be overwritten below

    // D -> offs[oc][px32] (aliased into samp), + bias, sigmoid masks.
    float* offs = (float*)samp;          // f32[27][32] = 3456 B
    if (wv < 2) {
        int n0 = wv * 16 + (lane & 15);
        int mB = cg * 4;
        if (n0 < 27) {
#pragma unroll
            for (int mt = 0; mt < 2; ++mt)
#pragma unroll
                for (int r = 0; r < 4; ++r) {
                    int pxc = mt * 16 + mB + r;
                    float vv = accO[mt][r] + sbuf[128 + n0];
                    if (n0 >= 18) vv = 1.0f / (1.0f + __expf(-vv));
                    offs[n0 * 32 + pxc] = vv;
                }
        }
    }
    __syncthreads();

    // ========= bilinear setup per (px,tap) -> LDS (corner-select folded into e-weights) =========
    // (writes eL -> rb row 2 dead from here on)
#pragma unroll
    for (int base = 0; base < 288; base += 256) {
        int idx = base + tid;
        if (idx < 288) {
            int px = idx & 31, tap = idx >> 5;
            float o1 = offs[(2 * tap) * 32 + px];
            float o2 = offs[(2 * tap + 1) * 32 + px];
            float m  = offs[(18 + tap) * 32 + px];
            float py  = (float)(h + tap / 3 - 1) + o1;
            float pxf = (float)(w0 + px + tap % 3 - 1) + o2;
            float y0f = floorf(py), x0f = floorf(pxf);
            float dy = py - y0f, dx = pxf - x0f;
            int y0 = (int)y0f, x0 = (int)x0f;
            int y1 = y0 + 1, x1 = x0 + 1;
            int yc0 = min(max(y0, 0), HH - 1), yc1 = min(max(y1, 0), HH - 1);
            int xc0 = min(max(x0, 0), WW - 1), xc1 = min(max(x1, 0), WW - 1);
            float vy0 = (y0 >= 0 && y0 < HH) ? 1.0f : 0.0f;
            float vy1 = (y1 >= 0 && y1 < HH) ? 1.0f : 0.0f;
            float vx0 = (x0 >= 0 && x0 < WW) ? 1.0f : 0.0f;
            float vx1 = (x1 >= 0 && x1 < WW) ? 1.0f : 0.0f;
            float c00 = (1.0f - dy) * (1.0f - dx) * m * vy0 * vx0;
            float c01 = (1.0f - dy) * dx * m * vy0 * vx1;
            float c10 = dy * (1.0f - dx) * m * vy1 * vx0;
            float c11 = dy * dx * m * vy1 * vx1;
            int bx = min(xc0, WW - 2);        // column pair [bx, bx+1] in-bounds
            bool s0 = (xc0 != bx), s1 = (xc1 != bx);
            eL[0][tap][px] = (s0 ? 0.f : c00) + (s1 ? 0.f : c01);
            eL[1][tap][px] = (s0 ? c00 : 0.f) + (s1 ? c01 : 0.f);
            eL[2][tap][px] = (s0 ? 0.f : c10) + (s1 ? 0.f : c11);
            eL[3][tap][px] = (s0 ? c10 : 0.f) + (s1 ? c11 : 0.f);
            oL[0][tap][px] = (yc0 * WW + bx) * 64;
            oL[1][tap][px] = (yc1 * WW + bx) * 64;
        }
    }
    __syncthreads();

    // ================= main conv via MFMA (3 chunks of 3 taps) =================
    // wave wv owns N-tile nt=wv, computes both M-tiles -> weights loaded once.
    f32x4 acc[2];
#pragma unroll
    for (int mt = 0; mt < 2; ++mt) acc[mt] = (f32x4){0.f, 0.f, 0.f, 0.f};

    for (int chk = 0; chk < 3; ++chk) {
#pragma unroll
        for (int tl = 0; tl < 3; ++tl) {
            int tap = chk * 3 + tl;
            int o0 = oL[0][tap][pxq], o1r = oL[1][tap][pxq];
            float e0 = eL[0][tap][pxq], e1 = eL[1][tap][pxq];
            float e2 = eL[2][tap][pxq], e3 = eL[3][tap][pxq];
            uint4 a0 = *(const uint4*)(xt + o0 + (c8 << 3));
            uint4 a1 = *(const uint4*)(xt + o0 + 64 + (c8 << 3));
            uint4 b0 = *(const uint4*)(xt + o1r + (c8 << 3));
            uint4 b1 = *(const uint4*)(xt + o1r + 64 + (c8 << 3));
            const unsigned int* pa0 = (const unsigned int*)&a0;
            const unsigned int* pa1 = (const unsigned int*)&a1;
            const unsigned int* pb0 = (const unsigned int*)&b0;
            const unsigned int* pb1 = (const unsigned int*)&b1;
            uint4 pk;
            unsigned int* pp = (unsigned int*)&pk;
#pragma unroll
            for (int q = 0; q < 4; ++q) {
                float lo = e0 * bf2f((unsigned short)(pa0[q] & 0xffff))
                         + e1 * bf2f((unsigned short)(pa1[q] & 0xffff))
                         + e2 * bf2f((unsigned short)(pb0[q] & 0xffff))
                         + e3 * bf2f((unsigned short)(pb1[q] & 0xffff));
                float hi = e0 * bf2f((unsigned short)(pa0[q] >> 16))
                         + e1 * bf2f((unsigned short)(pa1[q] >> 16))
                         + e2 * bf2f((unsigned short)(pb0[q] >> 16))
                         + e3 * bf2f((unsigned short)(pb1[q] >> 16));
                pp[q] = cvt_pk_bf16(lo, hi);
            }
            *(uint4*)&samp[pxq * KP2 + tl * 64 + (c8 << 3)] = pk;
        }
        __syncthreads();
        __builtin_amdgcn_s_setprio(1);
#pragma unroll
        for (int st = 0; st < 6; ++st) {
            int kb = chk * 6 + st;
            bf16x8 bf = WbM[(kb * 4 + wv) * 64 + lane];
            bf16x8 af0 = *(const bf16x8*)&samp[px16 * KP2 + st * 32 + (cg << 3)];
            bf16x8 af1 = *(const bf16x8*)&samp[(16 + px16) * KP2 + st * 32 + (cg << 3)];
            acc[0] = __builtin_amdgcn_mfma_f32_16x16x32_bf16(af0, bf, acc[0], 0, 0, 0);
            acc[1] = __builtin_amdgcn_mfma_f32_16x16x32_bf16(af1, bf, acc[1], 0, 0, 0);
        }
        __builtin_amdgcn_s_setprio(0);
        __syncthreads();
    }

    // ================= epilogue: transpose via LDS, BN + ReLU, coalesced stores ==========
    float* dT = (float*)samp;   // [64 o][33]; 8448 B <= 12800 B
    {
        int n0 = lane & 15;
        int mB = cg * 4;
#pragma unroll
        for (int mt = 0; mt < 2; ++mt)
#pragma unroll
            for (int r = 0; r < 4; ++r)
                dT[(wv * 16 + n0) * 33 + mt * 16 + mB + r] = acc[mt][r];
    }
    __syncthreads();
    {
        int px = tid & 31;
        int oh = tid >> 5;               // 0..7
#pragma unroll
        for (int i = 0; i < 8; ++i) {
            int o = 8 * i + oh;
            float v = dT[o * 33 + px];
            v = fmaxf(fmaf(v, sbuf[o], sbuf[64 + o]), 0.0f);
            out[(((size_t)(b * 64 + o)) << 14) + rem0 + px] = v;
        }
    }
}

extern "C" void kernel_launch(void* const* d_in, const int* in_sizes, int n_in,
                              void* d_out, int out_size, void* d_ws, size_t ws_size,
                              hipStream_t stream) {
    (void)in_sizes; (void)n_in; (void)ws_size; (void)out_size;
    const float* x     = (const float*)d_in[0];
    const float* w_off = (const float*)d_in[1];
    const float* b_off = (const float*)d_in[2];
    const float* wgt   = (const float*)d_in[3];
    const float* bias  = (const float*)d_in[4];
    const float* gamma = (const float*)d_in[5];
    const float* beta  = (const float*)d_in[6];
    const float* rmean = (const float*)d_in[7];
    const float* rvar  = (const float*)d_in[8];
    unsigned short* wsB = (unsigned short*)d_ws;
    float* outp = (float*)d_out;

    transpose_kernel<<<dim3(1024), dim3(256), 0, stream>>>(x, w_off, wgt, wsB);
    // 65536 px / 32 per block = 2048 blocks of 256 threads (4 waves each)
    DeformConv_14568529068723_kernel<<<dim3(2048), dim3(256), 0, stream>>>(
        b_off, bias, gamma, beta, rmean, rvar, wsB, outp);
}